// Round 13
// baseline (246.862 us; speedup 1.0000x reference)
//
#include <hip/hip_runtime.h>
#include <math.h>

#define SIM_T 100

// ---------------------------------------------------------------------------
// Transpose encW [out][in] -> encWT [in][out] (256KB, one-shot, ~2us).
// The only prep launch that survives R12's fusion.
// ---------------------------------------------------------------------------
__global__ __launch_bounds__(256) void k_transpose256(
    const float* __restrict__ W, float* __restrict__ WT) {
  int k = blockIdx.x;
  int o = threadIdx.x;
  WT[k * 256 + o] = W[o * 256 + k];
}

// ---------------------------------------------------------------------------
// R12 "MEGA": GEMM1 + sigmoid + GEMM2 + 100-step LIF sim in ONE kernel.
// Rationale: R8-R11 dispatch-time sums show ~10us/launch of graph gap (5
// launches = ~50us) and three structurally different GEMMs all plateaued --
// the constant was launch overhead + intermediate-tensor round-trips, not
// GEMM math. Dependencies are ROW-LOCAL (rates[b] -> c[b] -> sim(b)), so one
// block = 4 waves = 4 rows runs the whole chain:
//   Phase A: rates quad = sigmoid(sum_k x[r][k]*encWT[k][4l..4l+3] + b) ->
//            16B LDS stash (same-wave handoff, no barrier).
//   Phase B: c quad = (sum_k rates[k]*W1[k][4l..4l+3])*omd, rates read as
//            uniform ds_read_b128 broadcast; c stays IN REGISTERS.
//   Phase C: LIF sim (R11's k_sim verbatim, cv = register quad).
// W streams: coalesced float4 (1KB/instr); per 4k-iter 5 TA + 16 fma;
// 2048 blocks = 8/CU = 32 waves/CU hides L2 latency. No pack kernel, no
// packed layouts, no 8MB c/rates global round-trips.
// All fmaf chains k-ascending per output == R1..R11 exact order; sigmoid
// and *omd epilogues identical; sim identical -> absmax 0.0 preserved.
// ---------------------------------------------------------------------------
__global__ __launch_bounds__(256, 8) void k_mega(
    const float* __restrict__ x,      // [8192][256]
    const float* __restrict__ encWT,  // [256 k][256 o]
    const float* __restrict__ encB,   // [256]
    const float* __restrict__ W1,     // [256 k][256 o] (k-major as given)
    const float* __restrict__ W2,     // [256][256]
    const float* __restrict__ W3,     // [256][64]
    float* __restrict__ out, float decay, float omd) {
  __shared__ float4 shr[4 * 64];  // rates quads, 4KB
  const int lane = threadIdx.x & 63;
  const int w = threadIdx.x >> 6;
  const int row = blockIdx.x * 4 + w;

  // ================= Phase A: rates quad =================
  const float4* Wt4 = (const float4*)encWT + lane;  // [k][64 quads]
  const float* xr = x + (size_t)row * 256;
  float a0 = 0.f, a1 = 0.f, a2 = 0.f, a3 = 0.f;
#pragma unroll 4
  for (int k4 = 0; k4 < 64; k4++) {
    float4 xv = *(const float4*)(xr + k4 * 4);  // wave-uniform value, TA path
    float4 w0 = Wt4[(k4 * 4 + 0) * 64];
    float4 w1 = Wt4[(k4 * 4 + 1) * 64];
    float4 w2 = Wt4[(k4 * 4 + 2) * 64];
    float4 w3 = Wt4[(k4 * 4 + 3) * 64];
    // k ascending per output
    a0 = fmaf(xv.x, w0.x, a0);
    a1 = fmaf(xv.x, w0.y, a1);
    a2 = fmaf(xv.x, w0.z, a2);
    a3 = fmaf(xv.x, w0.w, a3);
    a0 = fmaf(xv.y, w1.x, a0);
    a1 = fmaf(xv.y, w1.y, a1);
    a2 = fmaf(xv.y, w1.z, a2);
    a3 = fmaf(xv.y, w1.w, a3);
    a0 = fmaf(xv.z, w2.x, a0);
    a1 = fmaf(xv.z, w2.y, a1);
    a2 = fmaf(xv.z, w2.z, a2);
    a3 = fmaf(xv.z, w2.w, a3);
    a0 = fmaf(xv.w, w3.x, a0);
    a1 = fmaf(xv.w, w3.y, a1);
    a2 = fmaf(xv.w, w3.z, a2);
    a3 = fmaf(xv.w, w3.w, a3);
  }
  {
    float4 bv = ((const float4*)encB)[lane];
    float4 rq;
    rq.x = 1.f / (1.f + expf(-(a0 + bv.x)));
    rq.y = 1.f / (1.f + expf(-(a1 + bv.y)));
    rq.z = 1.f / (1.f + expf(-(a2 + bv.z)));
    rq.w = 1.f / (1.f + expf(-(a3 + bv.w)));
    shr[w * 64 + lane] = rq;  // same-wave handoff; compiler emits lgkmcnt
  }

  // ================= Phase B: c quad =================
  const float4* W14 = (const float4*)W1 + lane;  // [k][64 quads]
  a0 = a1 = a2 = a3 = 0.f;
#pragma unroll 4
  for (int k4 = 0; k4 < 64; k4++) {
    float4 rv = shr[w * 64 + k4];  // uniform addr -> LDS broadcast
    float4 w0 = W14[(k4 * 4 + 0) * 64];
    float4 w1 = W14[(k4 * 4 + 1) * 64];
    float4 w2 = W14[(k4 * 4 + 2) * 64];
    float4 w3 = W14[(k4 * 4 + 3) * 64];
    a0 = fmaf(rv.x, w0.x, a0);
    a1 = fmaf(rv.x, w0.y, a1);
    a2 = fmaf(rv.x, w0.z, a2);
    a3 = fmaf(rv.x, w0.w, a3);
    a0 = fmaf(rv.y, w1.x, a0);
    a1 = fmaf(rv.y, w1.y, a1);
    a2 = fmaf(rv.y, w1.z, a2);
    a3 = fmaf(rv.y, w1.w, a3);
    a0 = fmaf(rv.z, w2.x, a0);
    a1 = fmaf(rv.z, w2.y, a1);
    a2 = fmaf(rv.z, w2.z, a2);
    a3 = fmaf(rv.z, w2.w, a3);
    a0 = fmaf(rv.w, w3.x, a0);
    a1 = fmaf(rv.w, w3.y, a1);
    a2 = fmaf(rv.w, w3.z, a2);
    a3 = fmaf(rv.w, w3.w, a3);
  }
  const float c0 = __fmul_rn(a0, omd);
  const float c1 = __fmul_rn(a1, omd);
  const float c2 = __fmul_rn(a2, omd);
  const float c3 = __fmul_rn(a3, omd);

  // ================= Phase C: LIF sim (R11 verbatim) =================
  float v10 = 0.f, v11 = 0.f, v12 = 0.f, v13 = 0.f;
  float v20 = 0.f, v21 = 0.f, v22 = 0.f, v23 = 0.f;
  float v3 = 0.f;
  int acc = 0;
  const float4* w2q = (const float4*)W2 + lane;  // w2q[r*64] = W2[r][4l..4l+3]
  const float* w3q = W3 + lane;

  for (int t = 0; t < SIM_T; t++) {
    // ---- layer 1 (constant input c) ----
    v10 = fmaf(v10, decay, c0);
    bool f0 = v10 >= 1.f;
    unsigned long long m0 = __ballot(f0);
    v10 = f0 ? 0.f : v10;
    v11 = fmaf(v11, decay, c1);
    bool f1 = v11 >= 1.f;
    unsigned long long m1 = __ballot(f1);
    v11 = f1 ? 0.f : v11;
    v12 = fmaf(v12, decay, c2);
    bool f2 = v12 >= 1.f;
    unsigned long long m2 = __ballot(f2);
    v12 = f2 ? 0.f : v12;
    v13 = fmaf(v13, decay, c3);
    bool f3 = v13 >= 1.f;
    unsigned long long m3 = __ballot(f3);
    v13 = f3 ? 0.f : v13;

    // ---- layer 2: sum W2 rows of spiking layer-1 neurons (id = 4*i+q) ----
    float s0 = 0.f, s1 = 0.f, s2 = 0.f, s3 = 0.f;
#define ACC2(mask, q)                             \
  {                                               \
    unsigned long long m = (mask);                \
    while (m) {                                   \
      int i = __builtin_ctzll(m);                 \
      m &= m - 1;                                 \
      float4 wv = w2q[i * 256 + (q) * 64];        \
      s0 += wv.x;                                 \
      s1 += wv.y;                                 \
      s2 += wv.z;                                 \
      s3 += wv.w;                                 \
    }                                             \
  }
    ACC2(m0, 0)
    ACC2(m1, 1)
    ACC2(m2, 2)
    ACC2(m3, 3)

    v20 = fmaf(v20, decay, __fmul_rn(s0, omd));
    bool g0 = v20 >= 1.f;
    unsigned long long n0 = __ballot(g0);
    v20 = g0 ? 0.f : v20;
    v21 = fmaf(v21, decay, __fmul_rn(s1, omd));
    bool g1 = v21 >= 1.f;
    unsigned long long n1 = __ballot(g1);
    v21 = g1 ? 0.f : v21;
    v22 = fmaf(v22, decay, __fmul_rn(s2, omd));
    bool g2 = v22 >= 1.f;
    unsigned long long n2 = __ballot(g2);
    v22 = g2 ? 0.f : v22;
    v23 = fmaf(v23, decay, __fmul_rn(s3, omd));
    bool g3 = v23 >= 1.f;
    unsigned long long n3 = __ballot(g3);
    v23 = g3 ? 0.f : v23;

    // ---- layer 3 (usually no layer-2 spikes: uniform skip) ----
    float z = 0.f;
    if (n0 | n1 | n2 | n3) {
#define ACC3(mask, q)                             \
  {                                               \
    unsigned long long m = (mask);                \
    while (m) {                                   \
      int i = __builtin_ctzll(m);                 \
      m &= m - 1;                                 \
      z += w3q[(i * 4 + (q)) * 64];               \
    }                                             \
  }
      ACC3(n0, 0)
      ACC3(n1, 1)
      ACC3(n2, 2)
      ACC3(n3, 3)
    }
    v3 = fmaf(v3, decay, __fmul_rn(z, omd));
    bool h = v3 >= 1.f;
    acc += h ? 1 : 0;
    v3 = h ? 0.f : v3;
  }
  out[(size_t)row * 64 + lane] = __fdiv_rn((float)acc, 100.f);
}

// ---------------------------------------------------------------------------
extern "C" void kernel_launch(void* const* d_in, const int* in_sizes, int n_in,
                              void* d_out, int out_size, void* d_ws,
                              size_t ws_size, hipStream_t stream) {
  const float* x = (const float*)d_in[0];     // [8192,256]
  const float* encW = (const float*)d_in[1];  // [256,256] (out,in)
  const float* encB = (const float*)d_in[2];  // [256]
  const float* W1 = (const float*)d_in[3];    // [256 k][256 o] k-major
  const float* W2 = (const float*)d_in[4];    // [256,256]
  const float* W3 = (const float*)d_in[5];    // [256,64]
  float* out = (float*)d_out;                 // [8192,64]

  float* encWT = (float*)d_ws;  // 256 KB

  const float decay = (float)exp((double)(-0.05f));
  const float omd = 1.0f - decay;

  k_transpose256<<<256, 256, 0, stream>>>(encW, encWT);
  k_mega<<<2048, 256, 0, stream>>>(x, encWT, encB, W1, W2, W3, out, decay,
                                   omd);
}